// Round 6
// baseline (474.605 us; speedup 1.0000x reference)
//
#include <hip/hip_runtime.h>

// ExpansionContrastModule on MI355X (gfx950), bf16 MFMA pipeline.
// All GEMMs on the proven 2-phase global_load_lds kernel (r2-verified;
// 8-phase arc removed after r3-r5 showed null-with-0-conflicts at 1 blk/CU).
// R6: G5 split-K x4 (atomic f32 out, norm-scaling moved into softmax_in);
// G7 fuses BatchNorm stats into its epilogue (NRM=2) and writes bf16,
// halving the BN chain's HBM traffic.

typedef unsigned short u16;
typedef unsigned int u32;
typedef __attribute__((ext_vector_type(4))) unsigned int u32x4;
typedef __attribute__((ext_vector_type(8))) short s16x8;
typedef __attribute__((ext_vector_type(4))) float f32x4;

#define DEVFN static __device__ __forceinline__

DEVFN u16 f2bf(float f) {
    u32 u = __builtin_bit_cast(u32, f);
    u32 r = (u + 0x7fffu + ((u >> 16) & 1u)) >> 16;  // RNE
    return (u16)r;
}
DEVFN float bf2f(u32 h) { u32 u = h << 16; return __builtin_bit_cast(float, u); }

typedef __attribute__((address_space(1))) const unsigned int gu32;
typedef __attribute__((address_space(3))) unsigned int lu32;
DEVFN void gld16(const void* g, void* l) {
    __builtin_amdgcn_global_load_lds((gu32*)g, (lu32*)l, 16, 0, 0);
}

// OFFSETS = [(-1,-1),(-1,0),(-1,1),(0,1),(1,1),(1,0),(1,-1),(0,-1)]
__constant__ int cOFFY[8] = {-1,-1,-1, 0, 1, 1, 1, 0};
__constant__ int cOFFX[8] = {-1, 0, 1, 1, 1, 0,-1,-1};

// XOR swizzle within a 128B LDS row (BK=64 bf16): measured 0 conflicts (r1-r5).
DEVFN int swz(int r, int kb) { return r * 128 + (kb ^ ((r & 7) << 4)); }

// ---------------------------------------------------------------------------
// 2-phase TN GEMM (verified rounds 1-5). BK=64, 256 thr = 4 waves (2x2),
// 64 KiB LDS -> 2 blocks/CU (TLP covers the barrier drain, m114).
// XG/YG: operand gathered from cen_t with dilated shifts (rows = area idx).
// DM: 0 = bf16 out, 1 = f32 out (atomicAdd when KSP>1), 2 = VLt scatter.
// NRM: 1 = accumulate ||row||^2 (bf16-rounded); 2 = accumulate per-row
//      (sum, sumsq) of raw f32 acc into nrm[row], nrm[256+row] (BN stats).
// KSP: split-K count (power of 2); blockIdx.y = ytile*KSP + kslice.
// ---------------------------------------------------------------------------
template<int BM, int BN, int WRM, int WRN, int XG, int YG, int DM, int NRM, int KSP>
__global__ __launch_bounds__(256, 2)
void gemm_tn(const u16* __restrict__ X, const u16* __restrict__ Y,
             void* __restrict__ D, const u16* __restrict__ cenT,
             const char* __restrict__ zeroPg, float* __restrict__ nrm,
             int K, int ldx, int ldy, int ldd, int sbits,
             long xb, long xs, long yb, long ys, long db, long dsn,
             long nb, long ns)
{
    static_assert(KSP == 1 || (!XG && !YG), "split-K only for non-gather");
    const int tid  = threadIdx.x;
    const int lane = tid & 63;
    const int wid  = tid >> 6;
    const int z = blockIdx.z;
    const int b = z >> sbits;
    const int s = z & ((1 << sbits) - 1);
    const int m0 = blockIdx.x * BM;
    const int ksl = (KSP > 1) ? (blockIdx.y & (KSP - 1)) : 0;
    const int n0 = (KSP > 1 ? (blockIdx.y / KSP) : blockIdx.y) * BN;
    const long koff = (long)ksl * (K / KSP);
    const int dil = s + 1;
    const int wm0 = (wid >> 1) * (WRM * 16);
    const int wn0 = (wid & 1) * (WRN * 16);

    __shared__ __align__(16) char lds[2 * (BM + BN) * 128];

    const char* cenB = (const char*)(cenT + (long)b * (4096 * 256));
    const char* Xb = nullptr;
    const char* Yb = nullptr;
    if constexpr (!XG) Xb = (const char*)(X + b * xb + (long)s * xs + (long)m0 * ldx + koff);
    if constexpr (!YG) Yb = (const char*)(Y + b * yb + (long)s * ys + (long)n0 * ldy + koff);

    auto stage = [&](int bf, int t) {
        char* LX = lds + bf * ((BM + BN) * 128);
        char* LY = LX + BM * 128;
        if constexpr (!XG) {
            const char* base = Xb + (long)t * 128;
            #pragma unroll
            for (int r = 0; r < BM / 32; r++) {
                const int R = r * 32 + wid * 8 + (lane >> 3);
                gld16(base + (long)R * (ldx * 2) + (((lane & 7) * 16) ^ ((R & 7) << 4)),
                      LX + (r * 32 + wid * 8) * 128);
            }
        } else {
            const int j = t >> 2;
            const int dy = cOFFY[j] * dil, dx = cOFFX[j] * dil;
            const int cb = (t & 3) * 128;
            #pragma unroll
            for (int r = 0; r < BM / 32; r++) {
                const int R = r * 32 + wid * 8 + (lane >> 3);
                const int a = m0 + R, yy = (a >> 6) + dy, xx = (a & 63) + dx;
                const int off = ((lane & 7) * 16) ^ ((R & 7) << 4);
                const char* src = (((unsigned)yy < 64u) && ((unsigned)xx < 64u))
                    ? cenB + ((long)((yy << 6) + xx) << 9) + cb + off
                    : zeroPg + off;
                gld16(src, LX + (r * 32 + wid * 8) * 128);
            }
        }
        if constexpr (!YG) {
            const char* base = Yb + (long)t * 128;
            #pragma unroll
            for (int r = 0; r < BN / 32; r++) {
                const int R = r * 32 + wid * 8 + (lane >> 3);
                gld16(base + (long)R * (ldy * 2) + (((lane & 7) * 16) ^ ((R & 7) << 4)),
                      LY + (r * 32 + wid * 8) * 128);
            }
        } else {
            const int j = t >> 2;
            const int dy = cOFFY[j] * dil, dx = cOFFX[j] * dil;
            const int cb = (t & 3) * 128;
            #pragma unroll
            for (int r = 0; r < BN / 32; r++) {
                const int R = r * 32 + wid * 8 + (lane >> 3);
                const int a = n0 + R, yy = (a >> 6) + dy, xx = (a & 63) + dx;
                const int off = ((lane & 7) * 16) ^ ((R & 7) << 4);
                const char* src = (((unsigned)yy < 64u) && ((unsigned)xx < 64u))
                    ? cenB + ((long)((yy << 6) + xx) << 9) + cb + off
                    : zeroPg + off;
                gld16(src, LY + (r * 32 + wid * 8) * 128);
            }
        }
    };

    f32x4 acc[WRM][WRN] = {};

    auto comp = [&](int bf) {
        const char* LX = lds + bf * ((BM + BN) * 128);
        const char* LY = LX + BM * 128;
        #pragma unroll
        for (int kk = 0; kk < 2; kk++) {
            const int kb = kk * 64 + ((lane >> 4) << 4);
            s16x8 af[WRM], bfr[WRN];
            #pragma unroll
            for (int m = 0; m < WRM; m++)
                af[m] = *(const s16x8*)(LX + swz(wm0 + m * 16 + (lane & 15), kb));
            #pragma unroll
            for (int n = 0; n < WRN; n++)
                bfr[n] = *(const s16x8*)(LY + swz(wn0 + n * 16 + (lane & 15), kb));
            #pragma unroll
            for (int m = 0; m < WRM; m++)
                #pragma unroll
                for (int n = 0; n < WRN; n++)
                    acc[m][n] = __builtin_amdgcn_mfma_f32_16x16x32_bf16(af[m], bfr[n], acc[m][n], 0, 0, 0);
        }
    };

    const int nt = (K / KSP) / 64;
    stage(0, 0);
    __syncthreads();
    int cur = 0;
    for (int t = 0; t < nt; t++) {
        if (t + 1 < nt) stage(cur ^ 1, t + 1);
        comp(cur);
        __syncthreads();
        cur ^= 1;
    }

    if constexpr (NRM) {
        float* nrmP = nrm + b * nb + s * ns;
        #pragma unroll
        for (int m = 0; m < WRM; m++) {
            float ss[4] = {0.f, 0.f, 0.f, 0.f};
            float s1v[4] = {0.f, 0.f, 0.f, 0.f};
            #pragma unroll
            for (int n = 0; n < WRN; n++)
                #pragma unroll
                for (int i = 0; i < 4; i++) {
                    float v = (NRM == 1) ? bf2f(f2bf(acc[m][n][i])) : acc[m][n][i];
                    ss[i] += v * v;
                    if constexpr (NRM == 2) s1v[i] += v;
                }
            #pragma unroll
            for (int o = 1; o < 16; o <<= 1)
                #pragma unroll
                for (int i = 0; i < 4; i++) {
                    ss[i] += __shfl_xor(ss[i], o);
                    if constexpr (NRM == 2) s1v[i] += __shfl_xor(s1v[i], o);
                }
            if ((lane & 15) == 0) {
                const int row0 = m0 + wm0 + m * 16 + ((lane >> 4) << 2);
                #pragma unroll
                for (int i = 0; i < 4; i++) {
                    if constexpr (NRM == 1) {
                        atomicAdd(&nrmP[row0 + i], ss[i]);
                    } else {
                        atomicAdd(&nrmP[row0 + i], s1v[i]);
                        atomicAdd(&nrmP[256 + row0 + i], ss[i]);
                    }
                }
            }
        }
    }

    // epilogue: D row = (lane>>4)*4 + i, col = lane&15
    #pragma unroll
    for (int m = 0; m < WRM; m++) {
        const int row0 = m0 + wm0 + m * 16 + ((lane >> 4) << 2);
        #pragma unroll
        for (int n = 0; n < WRN; n++) {
            const int col = n0 + wn0 + n * 16 + (lane & 15);
            f32x4 a = acc[m][n];
            if constexpr (DM == 1) {
                float* Dp = (float*)D + b * db + (long)s * dsn;
                #pragma unroll
                for (int i = 0; i < 4; i++) {
                    if constexpr (KSP > 1) atomicAdd(&Dp[(long)(row0 + i) * ldd + col], a[i]);
                    else Dp[(long)(row0 + i) * ldd + col] = a[i];
                }
            } else if constexpr (DM == 0) {
                u16* Dp = (u16*)D + b * db + (long)s * dsn;
                #pragma unroll
                for (int i = 0; i < 4; i++) Dp[(long)(row0 + i) * ldd + col] = f2bf(a[i]);
            } else {
                u16* Dp = (u16*)D;
                const int s2 = col >> 6, k2 = col & 63;
                const long base = (long)(b * 4 + s2) * 4096;
                #pragma unroll
                for (int i = 0; i < 4; i++)
                    Dp[(base + row0 + i) * 576 + 512 + k2] = f2bf(a[i]);
            }
        }
    }
}

// ---------------------------------------------------------------------------
// small kernels
// ---------------------------------------------------------------------------
__global__ __launch_bounds__(256) void zero_f32(float* __restrict__ p, int n) {
    int i = blockIdx.x * 256 + threadIdx.x;
    if (i < n) p[i] = 0.f;
}

__global__ void castbf(const float* __restrict__ src, u16* __restrict__ dst, int n8, float scale) {
    int i = blockIdx.x * 256 + threadIdx.x;
    if (i >= n8) return;
    const float* s = src + (long)i * 8;
    u32x4 o;
    #pragma unroll
    for (int j = 0; j < 4; j++) {
        u16 lo = f2bf(s[2 * j] * scale), hi = f2bf(s[2 * j + 1] * scale);
        o[j] = (u32)lo | ((u32)hi << 16);
    }
    *(u32x4*)(dst + (long)i * 8) = o;
}

// cen [b][256][4096] f32 -> cen_t [b][4096][256] bf16
__global__ __launch_bounds__(256) void transpose_cen(const float* __restrict__ cen, u16* __restrict__ cenT) {
    __shared__ float t[64][65];
    const int tx = threadIdx.x & 63, ty = threadIdx.x >> 6;
    const int a0 = blockIdx.x * 64, c0 = blockIdx.y * 64, b = blockIdx.z;
    const float* src = cen + ((long)(b * 256 + c0)) * 4096 + a0;
    #pragma unroll
    for (int i = 0; i < 16; i++) t[ty + i * 4][tx] = src[(long)(ty + i * 4) * 4096 + tx];
    __syncthreads();
    u16* dst = cenT + ((long)b * 4096 + a0) * 256 + c0;
    #pragma unroll
    for (int i = 0; i < 16; i++) dst[(long)(ty + i * 4) * 256 + tx] = f2bf(t[tx][ty + i * 4]);
}

// per (b,s): scale raw scores by 1/(|q||k|), instance-norm over [64][512],
// row softmax -> ws bf16 in WSWC[...][0:512], wc (sum of 8 chunks) -> [512:576]
__global__ __launch_bounds__(256) void softmax_in(const float* __restrict__ score,
                                                  const float* __restrict__ nQ,
                                                  const float* __restrict__ nK,
                                                  u16* __restrict__ wswc) {
    const int bs = blockIdx.x, tid = threadIdx.x;
    const int b = bs >> 2, s = bs & 3;
    const float* S = score + (long)bs * 32768;
    __shared__ float invq[64], invk[512];
    if (tid < 64) invq[tid] = 1.f / fmaxf(sqrtf(nQ[b * 256 + s * 64 + tid]), 1e-12f);
    for (int i = tid; i < 512; i += 256) invk[i] = 1.f / fmaxf(sqrtf(nK[bs * 512 + i]), 1e-12f);
    __syncthreads();
    float s1 = 0.f, s2 = 0.f;
    for (int i = tid; i < 32768; i += 256) {
        float v = S[i] * invq[i >> 9] * invk[i & 511];
        s1 += v; s2 += v * v;
    }
    __shared__ float ra[256], rb[256];
    ra[tid] = s1; rb[tid] = s2; __syncthreads();
    for (int st = 128; st > 0; st >>= 1) {
        if (tid < st) { ra[tid] += ra[tid + st]; rb[tid] += rb[tid + st]; }
        __syncthreads();
    }
    const float mu = ra[0] * (1.f / 32768.f);
    const float var = rb[0] * (1.f / 32768.f) - mu * mu;
    const float rstd = rsqrtf(var + 1e-5f);
    const int wid = tid >> 6, lane = tid & 63;
    u16* W = wswc + (long)bs * 64 * 576;
    for (int r = wid; r < 64; r += 4) {
        float zv[8]; float mx = -3.0e38f;
        const float iq = invq[r];
        #pragma unroll
        for (int i = 0; i < 8; i++) {
            const int c = i * 64 + lane;
            zv[i] = (S[r * 512 + c] * iq * invk[c] - mu) * rstd;
            mx = fmaxf(mx, zv[i]);
        }
        #pragma unroll
        for (int o = 32; o > 0; o >>= 1) mx = fmaxf(mx, __shfl_xor(mx, o));
        float sum = 0.f;
        #pragma unroll
        for (int i = 0; i < 8; i++) { zv[i] = __expf(zv[i] - mx); sum += zv[i]; }
        #pragma unroll
        for (int o = 32; o > 0; o >>= 1) sum += __shfl_xor(sum, o);
        const float inv = 1.f / sum;
        float wcv = 0.f;
        #pragma unroll
        for (int i = 0; i < 8; i++) {
            float w = zv[i] * inv; wcv += w;
            W[r * 576 + i * 64 + lane] = f2bf(w);
        }
        W[r * 576 + 512 + lane] = f2bf(wcv);
    }
}

// BN finalize: bnacc[c]=sum, bnacc[256+c]=sumsq over (b=4, area=4096)
__global__ __launch_bounds__(256) void bn_finalize(const float* __restrict__ bnacc,
                                                   const float* __restrict__ gamma,
                                                   const float* __restrict__ beta,
                                                   float* __restrict__ st) {
    const int c = threadIdx.x;
    const float mu = bnacc[c] * (1.f / 16384.f);
    const float var = bnacc[256 + c] * (1.f / 16384.f) - mu * mu;
    const float g = gamma[c] * rsqrtf(var + 1e-5f);
    st[c * 2] = g;
    st[c * 2 + 1] = beta[c] - mu * g;
}

// apply BN+ReLU: out2b bf16 [b][256][4096] -> out f32
__global__ __launch_bounds__(256) void bn_apply(const u16* __restrict__ out2b,
                                                const float* __restrict__ st,
                                                float* __restrict__ out) {
    const long i8 = (long)blockIdx.x * 256 + threadIdx.x;
    const u32x4 v = *(const u32x4*)(out2b + i8 * 8);
    const int c = (int)((i8 * 8) >> 12) & 255;
    const float g = st[c * 2], bt = st[c * 2 + 1];
    float* o = out + i8 * 8;
    #pragma unroll
    for (int j = 0; j < 4; j++) {
        o[2 * j]     = fmaxf(bf2f(v[j] & 0xffff) * g + bt, 0.f);
        o[2 * j + 1] = fmaxf(bf2f(v[j] >> 16) * g + bt, 0.f);
    }
}

// ---------------------------------------------------------------------------
extern "C" void kernel_launch(void* const* d_in, const int* in_sizes, int n_in,
                              void* d_out, int out_size, void* d_ws, size_t ws_size,
                              hipStream_t stream) {
    (void)in_sizes; (void)n_in; (void)out_size; (void)ws_size;
    const float* cen   = (const float*)d_in[0];
    const float* qw    = (const float*)d_in[1];
    const float* lw    = (const float*)d_in[2];
    const float* kw    = (const float*)d_in[3];
    const float* vw    = (const float*)d_in[4];
    const float* ow    = (const float*)d_in[5];
    const float* gamma = (const float*)d_in[6];
    const float* beta  = (const float*)d_in[7];
    float* out = (float*)d_out;

    char* ws = (char*)d_ws;
    size_t off = 0;
    auto alloc = [&](size_t bytes) { size_t o = off; off += (bytes + 255) & ~(size_t)255; return o; };
    u16*   KWb   = (u16*)(ws + alloc(4L * 512 * 2048 * 2));
    u16*   VWb   = (u16*)(ws + alloc(4L * 512 * 2048 * 2));
    u16*   QWb   = (u16*)(ws + alloc(256L * 256 * 2));
    u16*   LWnb  = (u16*)(ws + alloc(256L * 256 * 2));
    u16*   OWb   = (u16*)(ws + alloc(256L * 256 * 2));
    u16*   cenT  = (u16*)(ws + alloc(4L * 4096 * 256 * 2));
    u16*   keys  = (u16*)(ws + alloc(16L * 512 * 4096 * 2));
    u16*   qs    = (u16*)(ws + alloc(16L * 64 * 4096 * 2));
    u16*   VLt   = (u16*)(ws + alloc(16L * 4096 * 576 * 2));
    float* score = (float*)(ws + alloc(16L * 64 * 512 * 4));
    u16*   WSWC  = (u16*)(ws + alloc(16L * 64 * 576 * 2));
    u16*   out1t = (u16*)(ws + alloc(4L * 4096 * 256 * 2));
    u16*   out2b = (u16*)(ws + alloc(4L * 256 * 4096 * 2));
    float* bnst  = (float*)(ws + alloc(256L * 2 * 4));
    float* nrmB  = (float*)(ws + alloc((64L + 8192 + 1024 + 512) * 4));
    char*  zpg   = (char*)nrmB;           // 256B zero page
    float* nK    = nrmB + 64;             // [b][s][512] ||key row||^2
    float* nQ    = nrmB + 64 + 8192;      // [b][256]    ||q row||^2
    float* bnacc = nrmB + 64 + 8192 + 1024; // [512] BN sum/sumsq

    // prep: zero accumulators (nrm block + split-K score), cast weights
    zero_f32<<<dim3(39),   256, 0, stream>>>(nrmB, 9792);
    zero_f32<<<dim3(2048), 256, 0, stream>>>(score, 524288);
    castbf<<<dim3(2048), 256, 0, stream>>>(kw, KWb, 524288, 1.f);
    castbf<<<dim3(2048), 256, 0, stream>>>(vw, VWb, 524288, 1.f);
    castbf<<<dim3(32),   256, 0, stream>>>(qw, QWb, 8192, 1.f);
    castbf<<<dim3(32),   256, 0, stream>>>(lw, LWnb, 8192, -1.f);
    castbf<<<dim3(32),   256, 0, stream>>>(ow, OWb, 8192, 1.f);
    transpose_cen<<<dim3(64, 4, 4), 256, 0, stream>>>(cen, cenT);

    // G1 keys[bs][512][4096] = KW[s] · surr_t(b,s)^T  (Y gathered) + key norms
    gemm_tn<128,128,4,4, 0,1, 0, 1, 1><<<dim3(4, 32, 16), 256, 0, stream>>>(
        KWb, nullptr, keys, cenT, zpg, nK,
        2048, 2048, 0, 4096, 2,
        0L, 512L * 2048, 0L, 0L, 4L * 512 * 4096, 512L * 4096, 2048L, 512L);
    // G2 vals_t into VLt[...][0:512] = surr_t(b,s) · VW[s]^T  (X gathered)
    gemm_tn<128,128,4,4, 1,0, 0, 0, 1><<<dim3(32, 4, 16), 256, 0, stream>>>(
        nullptr, VWb, VLt, cenT, zpg, nullptr,
        2048, 0, 2048, 576, 2,
        0L, 0L, 0L, 512L * 2048, 4L * 4096 * 576, 4096L * 576, 0L, 0L);
    // G3 qs[b][256][4096] = QW_all · cen_t[b]^T  + q norms
    gemm_tn<128,128,4,4, 0,0, 0, 1, 1><<<dim3(2, 32, 4), 256, 0, stream>>>(
        QWb, cenT, qs, cenT, zpg, nQ,
        256, 256, 256, 4096, 0,
        0L, 0L, 4096L * 256, 0L, 256L * 4096, 0L, 256L, 0L);
    // G4 -locs_t scattered into VLt[...][512:576] = cen_t[b] · (-LW_all)^T
    gemm_tn<128,128,4,4, 0,0, 2, 0, 1><<<dim3(32, 2, 4), 256, 0, stream>>>(
        cenT, LWnb, VLt, cenT, zpg, nullptr,
        256, 256, 256, 0, 0,
        4096L * 256, 0L, 0L, 0L, 0L, 0L, 0L, 0L);

    // G5 raw score[bs][64][512] = qs · keys^T, split-K x4 (atomic f32)
    gemm_tn<64,64,2,2, 0,0, 1, 0, 4><<<dim3(1, 32, 16), 256, 0, stream>>>(
        qs, keys, score, cenT, zpg, nullptr,
        4096, 4096, 4096, 512, 2,
        256L * 4096, 64L * 4096, 4L * 512 * 4096, 512L * 4096, 4L * 64 * 512, 64L * 512, 0L, 0L);

    // scale + instance-norm + softmax (+ wc)
    softmax_in<<<dim3(16), 256, 0, stream>>>(score, nQ, nK, WSWC);

    // G6 out1_t[b][4096][s*64+h] = VLt[bs] · WSWC[bs]^T  (K=576)
    gemm_tn<128,64,4,2, 0,0, 0, 0, 1><<<dim3(32, 1, 16), 256, 0, stream>>>(
        VLt, WSWC, out1t, cenT, zpg, nullptr,
        576, 576, 576, 256, 2,
        4L * 4096 * 576, 4096L * 576, 4L * 64 * 576, 64L * 576, 4096L * 256, 64L, 0L, 0L);
    // G7 out2b[b][256][4096] (bf16) = OW · out1_t[b]^T  + BN stat atomics
    gemm_tn<128,128,4,4, 0,0, 0, 2, 1><<<dim3(2, 32, 4), 256, 0, stream>>>(
        OWb, out1t, out2b, cenT, zpg, bnacc,
        256, 256, 256, 4096, 0,
        0L, 0L, 4096L * 256, 0L, 256L * 4096, 0L, 0L, 0L);

    bn_finalize<<<dim3(1), 256, 0, stream>>>(bnacc, gamma, beta, bnst);
    bn_apply<<<dim3(2048), 256, 0, stream>>>(out2b, bnst, out);
}

// Round 9
// 340.051 us; speedup vs baseline: 1.3957x; 1.3957x over previous
//
#include <hip/hip_runtime.h>

// ExpansionContrastModule on MI355X (gfx950), bf16 MFMA pipeline.
// R7 restructure (associativity): out = ws·(VW·surr) - wc·(LW·cen) computed
// as (ws·VW)·surr - (wc·LW)·cen -> deletes the 137-GFLOP vals GEMM.
// R9: FULLY DETERMINISTIC, fixed. No atomics anywhere; norm/BN partials are
// single-writer per (row, N-block, N-half-wave) slot — r8's bug was two
// N-half waves sharing one slot (last-writer-wins, half the sum). Every
// partial slot is rewritten every call -> graph replays are bit-identical.

typedef unsigned short u16;
typedef unsigned int u32;
typedef __attribute__((ext_vector_type(4))) unsigned int u32x4;
typedef __attribute__((ext_vector_type(8))) short s16x8;
typedef __attribute__((ext_vector_type(4))) float f32x4;

#define DEVFN static __device__ __forceinline__

DEVFN u16 f2bf(float f) {
    u32 u = __builtin_bit_cast(u32, f);
    u32 r = (u + 0x7fffu + ((u >> 16) & 1u)) >> 16;  // RNE
    return (u16)r;
}
DEVFN float bf2f(u32 h) { u32 u = h << 16; return __builtin_bit_cast(float, u); }

typedef __attribute__((address_space(1))) const unsigned int gu32;
typedef __attribute__((address_space(3))) unsigned int lu32;
DEVFN void gld16(const void* g, void* l) {
    __builtin_amdgcn_global_load_lds((gu32*)g, (lu32*)l, 16, 0, 0);
}

// OFFSETS = [(-1,-1),(-1,0),(-1,1),(0,1),(1,1),(1,0),(1,-1),(0,-1)]
__constant__ int cOFFY[8] = {-1,-1,-1, 0, 1, 1, 1, 0};
__constant__ int cOFFX[8] = {-1, 0, 1, 1, 1, 0,-1,-1};

// XOR swizzle within a 128B LDS row (BK=64 bf16): measured 0 conflicts (r1-r6).
DEVFN int swz(int r, int kb) { return r * 128 + (kb ^ ((r & 7) << 4)); }

// ---------------------------------------------------------------------------
// 2-phase TN GEMM (verified rounds 1-6). BK=64, 256 thr = 4 waves (2x2),
// 64 KiB LDS -> 2 blocks/CU.
// XG/YG: operand gathered from cen_t; k<2048 -> offset j=k>>8 shifted by
// dilation, k>=2048 -> unshifted cen_t rows (G6n's K=2304).
// DM: 0 = bf16 out, 1 = f32 out.
// NRM (deterministic partials, single writer per slot; slot encodes the
// N-block AND the wave's N-half so no two waves share a slot):
//  1 = per-row ||row||^2 partial (bf16-rounded) ->
//      nrm[(b*nb + s*ns + row)*64 + blockIdx.y*2 + (wid&1)]
//  2 = per-row (sum, sumsq) of raw f32 acc ->
//      nrm[row*256 + b*64 + blockIdx.y*2 + (wid&1)], sumsq plane at +65536.
// ---------------------------------------------------------------------------
template<int BM, int BN, int WRM, int WRN, int XG, int YG, int DM, int NRM>
__global__ __launch_bounds__(256, 2)
void gemm_tn(const u16* __restrict__ X, const u16* __restrict__ Y,
             void* __restrict__ D, const u16* __restrict__ cenT,
             const char* __restrict__ zeroPg, float* __restrict__ nrm,
             int K, int ldx, int ldy, int ldd, int sbits,
             long xb, long xs, long yb, long ys, long db, long dsn,
             long nb, long ns)
{
    const int tid  = threadIdx.x;
    const int lane = tid & 63;
    const int wid  = tid >> 6;
    const int z = blockIdx.z;
    const int b = z >> sbits;
    const int s = z & ((1 << sbits) - 1);
    const int m0 = blockIdx.x * BM;
    const int n0 = blockIdx.y * BN;
    const int dil = s + 1;
    const int wm0 = (wid >> 1) * (WRM * 16);
    const int wn0 = (wid & 1) * (WRN * 16);

    __shared__ __align__(16) char lds[2 * (BM + BN) * 128];

    const char* cenB = (const char*)(cenT + (long)b * (4096 * 256));
    const char* Xb = nullptr;
    const char* Yb = nullptr;
    if constexpr (!XG) Xb = (const char*)(X + b * xb + (long)s * xs + (long)m0 * ldx);
    if constexpr (!YG) Yb = (const char*)(Y + b * yb + (long)s * ys + (long)n0 * ldy);

    auto stage = [&](int bf, int t) {
        char* LX = lds + bf * ((BM + BN) * 128);
        char* LY = LX + BM * 128;
        if constexpr (!XG) {
            const char* base = Xb + (long)t * 128;
            #pragma unroll
            for (int r = 0; r < BM / 32; r++) {
                const int R = r * 32 + wid * 8 + (lane >> 3);
                gld16(base + (long)R * (ldx * 2) + (((lane & 7) * 16) ^ ((R & 7) << 4)),
                      LX + (r * 32 + wid * 8) * 128);
            }
        } else {
            const int j = t >> 2;
            const int dy = (j < 8) ? cOFFY[j] * dil : 0;
            const int dx = (j < 8) ? cOFFX[j] * dil : 0;
            const int cb = (t & 3) * 128;
            #pragma unroll
            for (int r = 0; r < BM / 32; r++) {
                const int R = r * 32 + wid * 8 + (lane >> 3);
                const int a = m0 + R, yy = (a >> 6) + dy, xx = (a & 63) + dx;
                const int off = ((lane & 7) * 16) ^ ((R & 7) << 4);
                const char* src = (((unsigned)yy < 64u) && ((unsigned)xx < 64u))
                    ? cenB + ((long)((yy << 6) + xx) << 9) + cb + off
                    : zeroPg + off;
                gld16(src, LX + (r * 32 + wid * 8) * 128);
            }
        }
        if constexpr (!YG) {
            const char* base = Yb + (long)t * 128;
            #pragma unroll
            for (int r = 0; r < BN / 32; r++) {
                const int R = r * 32 + wid * 8 + (lane >> 3);
                gld16(base + (long)R * (ldy * 2) + (((lane & 7) * 16) ^ ((R & 7) << 4)),
                      LY + (r * 32 + wid * 8) * 128);
            }
        } else {
            const int j = t >> 2;
            const int dy = (j < 8) ? cOFFY[j] * dil : 0;
            const int dx = (j < 8) ? cOFFX[j] * dil : 0;
            const int cb = (t & 3) * 128;
            #pragma unroll
            for (int r = 0; r < BN / 32; r++) {
                const int R = r * 32 + wid * 8 + (lane >> 3);
                const int a = n0 + R, yy = (a >> 6) + dy, xx = (a & 63) + dx;
                const int off = ((lane & 7) * 16) ^ ((R & 7) << 4);
                const char* src = (((unsigned)yy < 64u) && ((unsigned)xx < 64u))
                    ? cenB + ((long)((yy << 6) + xx) << 9) + cb + off
                    : zeroPg + off;
                gld16(src, LY + (r * 32 + wid * 8) * 128);
            }
        }
    };

    f32x4 acc[WRM][WRN] = {};

    auto comp = [&](int bf) {
        const char* LX = lds + bf * ((BM + BN) * 128);
        const char* LY = LX + BM * 128;
        #pragma unroll
        for (int kk = 0; kk < 2; kk++) {
            const int kb = kk * 64 + ((lane >> 4) << 4);
            s16x8 af[WRM], bfr[WRN];
            #pragma unroll
            for (int m = 0; m < WRM; m++)
                af[m] = *(const s16x8*)(LX + swz(wm0 + m * 16 + (lane & 15), kb));
            #pragma unroll
            for (int n = 0; n < WRN; n++)
                bfr[n] = *(const s16x8*)(LY + swz(wn0 + n * 16 + (lane & 15), kb));
            #pragma unroll
            for (int m = 0; m < WRM; m++)
                #pragma unroll
                for (int n = 0; n < WRN; n++)
                    acc[m][n] = __builtin_amdgcn_mfma_f32_16x16x32_bf16(af[m], bfr[n], acc[m][n], 0, 0, 0);
        }
    };

    const int nt = K / 64;
    stage(0, 0);
    __syncthreads();
    int cur = 0;
    for (int t = 0; t < nt; t++) {
        if (t + 1 < nt) stage(cur ^ 1, t + 1);
        comp(cur);
        __syncthreads();
        cur ^= 1;
    }

    if constexpr (NRM) {
        const int slot = (blockIdx.y << 1) + (wid & 1);
        #pragma unroll
        for (int m = 0; m < WRM; m++) {
            float ss[4] = {0.f, 0.f, 0.f, 0.f};
            float s1v[4] = {0.f, 0.f, 0.f, 0.f};
            #pragma unroll
            for (int n = 0; n < WRN; n++)
                #pragma unroll
                for (int i = 0; i < 4; i++) {
                    float v = (NRM == 1) ? bf2f(f2bf(acc[m][n][i])) : acc[m][n][i];
                    ss[i] += v * v;
                    if constexpr (NRM == 2) s1v[i] += v;
                }
            #pragma unroll
            for (int o = 1; o < 16; o <<= 1)
                #pragma unroll
                for (int i = 0; i < 4; i++) {
                    ss[i] += __shfl_xor(ss[i], o);
                    if constexpr (NRM == 2) s1v[i] += __shfl_xor(s1v[i], o);
                }
            if ((lane & 15) == 0) {
                const int row0 = m0 + wm0 + m * 16 + ((lane >> 4) << 2);
                #pragma unroll
                for (int i = 0; i < 4; i++) {
                    if constexpr (NRM == 1) {
                        nrm[((long)(b * nb + s * ns + row0 + i) << 6) + slot] = ss[i];
                    } else {
                        float* p = nrm + ((long)(row0 + i) << 8) + (b << 6) + slot;
                        p[0] = s1v[i];
                        p[65536] = ss[i];
                    }
                }
            }
        }
    }

    // epilogue: D row = (lane>>4)*4 + i, col = lane&15
    #pragma unroll
    for (int m = 0; m < WRM; m++) {
        const int row0 = m0 + wm0 + m * 16 + ((lane >> 4) << 2);
        #pragma unroll
        for (int n = 0; n < WRN; n++) {
            const int col = n0 + wn0 + n * 16 + (lane & 15);
            f32x4 a = acc[m][n];
            if constexpr (DM == 1) {
                float* Dp = (float*)D + b * db + (long)s * dsn;
                #pragma unroll
                for (int i = 0; i < 4; i++) Dp[(long)(row0 + i) * ldd + col] = a[i];
            } else {
                u16* Dp = (u16*)D + b * db + (long)s * dsn;
                #pragma unroll
                for (int i = 0; i < 4; i++) Dp[(long)(row0 + i) * ldd + col] = f2bf(a[i]);
            }
        }
    }
}

// ---------------------------------------------------------------------------
// small kernels
// ---------------------------------------------------------------------------
__global__ __launch_bounds__(256) void zero_f32(float* __restrict__ p, int n) {
    int i = blockIdx.x * 256 + threadIdx.x;
    if (i < n) p[i] = 0.f;
}

__global__ void castbf(const float* __restrict__ src, u16* __restrict__ dst, int n8, float scale) {
    int i = blockIdx.x * 256 + threadIdx.x;
    if (i >= n8) return;
    const float* s = src + (long)i * 8;
    u32x4 o;
    #pragma unroll
    for (int j = 0; j < 4; j++) {
        u16 lo = f2bf(s[2 * j] * scale), hi = f2bf(s[2 * j + 1] * scale);
        o[j] = (u32)lo | ((u32)hi << 16);
    }
    *(u32x4*)(dst + (long)i * 8) = o;
}

// generic transpose+cast: src f32 [z][R][C] -> dst bf16 [z][C][R] * scale
__global__ __launch_bounds__(256) void transpose_cast(const float* __restrict__ src, u16* __restrict__ dst,
                                                      int R, int C, float scale) {
    __shared__ float t[64][65];
    const int tx = threadIdx.x & 63, ty = threadIdx.x >> 6;
    const int c0 = blockIdx.x * 64, r0 = blockIdx.y * 64;
    const long bb = (long)blockIdx.z * R * C;
    const float* s = src + bb + (long)r0 * C + c0;
    #pragma unroll
    for (int i = 0; i < 16; i++) t[ty + i * 4][tx] = s[(long)(ty + i * 4) * C + tx];
    __syncthreads();
    u16* d = dst + bb + (long)c0 * R + r0;
    #pragma unroll
    for (int i = 0; i < 16; i++) d[(long)(ty + i * 4) * R + tx] = f2bf(t[tx][ty + i * 4] * scale);
}

// per (b,s): reduce norm partials (64 each), scale scores by 1/(|q||k|),
// instance-norm over [64][512], row softmax -> ws bf16 -> WSWC[...][0:512],
// wc (sum of 8 chunks) -> [512:576]
__global__ __launch_bounds__(256) void softmax_in(const float* __restrict__ score,
                                                  const float* __restrict__ nQp,
                                                  const float* __restrict__ nKp,
                                                  u16* __restrict__ wswc) {
    const int bs = blockIdx.x, tid = threadIdx.x;
    const int b = bs >> 2, s = bs & 3;
    const float* S = score + (long)bs * 32768;
    __shared__ float invq[64], invk[512];
    if (tid < 64) {
        const float* p = nQp + ((long)(b * 256 + s * 64 + tid) << 6);
        float a = 0.f;
        #pragma unroll
        for (int j = 0; j < 64; j++) a += p[j];
        invq[tid] = 1.f / fmaxf(sqrtf(a), 1e-12f);
    }
    for (int i = tid; i < 512; i += 256) {
        const float* p = nKp + (((long)bs * 512 + i) << 6);
        float a = 0.f;
        #pragma unroll
        for (int j = 0; j < 64; j++) a += p[j];
        invk[i] = 1.f / fmaxf(sqrtf(a), 1e-12f);
    }
    __syncthreads();
    float s1 = 0.f, s2 = 0.f;
    for (int i = tid; i < 32768; i += 256) {
        float v = S[i] * invq[i >> 9] * invk[i & 511];
        s1 += v; s2 += v * v;
    }
    __shared__ float ra[256], rb[256];
    ra[tid] = s1; rb[tid] = s2; __syncthreads();
    for (int st = 128; st > 0; st >>= 1) {
        if (tid < st) { ra[tid] += ra[tid + st]; rb[tid] += rb[tid + st]; }
        __syncthreads();
    }
    const float mu = ra[0] * (1.f / 32768.f);
    const float var = rb[0] * (1.f / 32768.f) - mu * mu;
    const float rstd = rsqrtf(var + 1e-5f);
    const int wid = tid >> 6, lane = tid & 63;
    u16* W = wswc + (long)bs * 64 * 576;
    for (int r = wid; r < 64; r += 4) {
        float zv[8]; float mx = -3.0e38f;
        const float iq = invq[r];
        #pragma unroll
        for (int i = 0; i < 8; i++) {
            const int c = i * 64 + lane;
            zv[i] = (S[r * 512 + c] * iq * invk[c] - mu) * rstd;
            mx = fmaxf(mx, zv[i]);
        }
        #pragma unroll
        for (int o = 32; o > 0; o >>= 1) mx = fmaxf(mx, __shfl_xor(mx, o));
        float sum = 0.f;
        #pragma unroll
        for (int i = 0; i < 8; i++) { zv[i] = __expf(zv[i] - mx); sum += zv[i]; }
        #pragma unroll
        for (int o = 32; o > 0; o >>= 1) sum += __shfl_xor(sum, o);
        const float inv = 1.f / sum;
        float wcv = 0.f;
        #pragma unroll
        for (int i = 0; i < 8; i++) {
            float w = zv[i] * inv; wcv += w;
            W[r * 576 + i * 64 + lane] = f2bf(w);
        }
        W[r * 576 + 512 + lane] = f2bf(wcv);
    }
}

// BN finalize from partials: bnp[c*256 + j] = sum partial, +65536 = sumsq
__global__ __launch_bounds__(256) void bn_finalize(const float* __restrict__ bnp,
                                                   const float* __restrict__ gamma,
                                                   const float* __restrict__ beta,
                                                   float* __restrict__ st) {
    const int c = threadIdx.x;
    const float* p = bnp + ((long)c << 8);
    float s1 = 0.f, s2 = 0.f;
    #pragma unroll 8
    for (int j = 0; j < 256; j++) { s1 += p[j]; s2 += p[65536 + j]; }
    const float mu = s1 * (1.f / 16384.f);
    const float var = s2 * (1.f / 16384.f) - mu * mu;
    const float g = gamma[c] * rsqrtf(var + 1e-5f);
    st[c * 2] = g;
    st[c * 2 + 1] = beta[c] - mu * g;
}

// apply BN+ReLU: out2b bf16 [b][256][4096] -> out f32
__global__ __launch_bounds__(256) void bn_apply(const u16* __restrict__ out2b,
                                                const float* __restrict__ st,
                                                float* __restrict__ out) {
    const long i8 = (long)blockIdx.x * 256 + threadIdx.x;
    const u32x4 v = *(const u32x4*)(out2b + i8 * 8);
    const int c = (int)((i8 * 8) >> 12) & 255;
    const float g = st[c * 2], bt = st[c * 2 + 1];
    float* o = out + i8 * 8;
    #pragma unroll
    for (int j = 0; j < 4; j++) {
        o[2 * j]     = fmaxf(bf2f(v[j] & 0xffff) * g + bt, 0.f);
        o[2 * j + 1] = fmaxf(bf2f(v[j] >> 16) * g + bt, 0.f);
    }
}

// ---------------------------------------------------------------------------
extern "C" void kernel_launch(void* const* d_in, const int* in_sizes, int n_in,
                              void* d_out, int out_size, void* d_ws, size_t ws_size,
                              hipStream_t stream) {
    (void)in_sizes; (void)n_in; (void)out_size; (void)ws_size;
    const float* cen   = (const float*)d_in[0];
    const float* qw    = (const float*)d_in[1];
    const float* lw    = (const float*)d_in[2];
    const float* kw    = (const float*)d_in[3];
    const float* vw    = (const float*)d_in[4];
    const float* ow    = (const float*)d_in[5];
    const float* gamma = (const float*)d_in[6];
    const float* beta  = (const float*)d_in[7];
    float* out = (float*)d_out;

    char* ws = (char*)d_ws;
    size_t off = 0;
    auto alloc = [&](size_t bytes) { size_t o = off; off += (bytes + 255) & ~(size_t)255; return o; };
    u16*   KWb   = (u16*)(ws + alloc(4L * 512 * 2048 * 2));
    u16*   VWt   = (u16*)(ws + alloc(4L * 2048 * 512 * 2));   // vw^T per s
    u16*   QWb   = (u16*)(ws + alloc(256L * 256 * 2));
    u16*   LWt   = (u16*)(ws + alloc(4L * 256 * 64 * 2));     // -lw^T per s
    u16*   OWb   = (u16*)(ws + alloc(256L * 256 * 2));
    u16*   cenT  = (u16*)(ws + alloc(4L * 4096 * 256 * 2));
    u16*   keys  = (u16*)(ws + alloc(16L * 512 * 4096 * 2));
    u16*   qs    = (u16*)(ws + alloc(16L * 64 * 4096 * 2));
    float* score = (float*)(ws + alloc(16L * 64 * 512 * 4));
    u16*   WSWC  = (u16*)(ws + alloc(16L * 64 * 576 * 2));
    u16*   Xcomb = (u16*)(ws + alloc(16L * 64 * 2304 * 2));   // [E | F] per (b,s)
    u16*   out1t = (u16*)(ws + alloc(4L * 4096 * 256 * 2));
    u16*   out2b = (u16*)(ws + alloc(4L * 256 * 4096 * 2));
    float* bnst  = (float*)(ws + alloc(256L * 2 * 4));
    char*  zpg   = (char*)(ws + alloc(256));                  // 256B zero page
    float* nKp   = (float*)(ws + alloc(16L * 512 * 64 * 4));  // key norm partials
    float* nQp   = (float*)(ws + alloc(4L * 256 * 64 * 4));   // q norm partials
    float* bnp   = (float*)(ws + alloc(2L * 65536 * 4));      // BN sum/sumsq partials

    // prep: zero the 256B zero page; cast/transpose weights; transpose cen.
    // (Partial buffers need no zeroing: every slot is rewritten every call.)
    zero_f32<<<dim3(1), 256, 0, stream>>>((float*)zpg, 64);
    castbf<<<dim3(2048), 256, 0, stream>>>(kw, KWb, 524288, 1.f);
    castbf<<<dim3(32),   256, 0, stream>>>(qw, QWb, 8192, 1.f);
    castbf<<<dim3(32),   256, 0, stream>>>(ow, OWb, 8192, 1.f);
    transpose_cast<<<dim3(32, 8, 4), 256, 0, stream>>>(vw, VWt, 512, 2048, 1.f);
    transpose_cast<<<dim3(4, 1, 4),  256, 0, stream>>>(lw, LWt, 64, 256, -1.f);
    transpose_cast<<<dim3(64, 4, 4), 256, 0, stream>>>(cen, cenT, 256, 4096, 1.f);

    // G1 keys[bs][512][4096] = KW[s] · surr_t(b,s)^T (Y gathered) + norm partials
    gemm_tn<128,128,4,4, 0,1, 0, 1><<<dim3(4, 32, 16), 256, 0, stream>>>(
        KWb, nullptr, keys, cenT, zpg, nKp,
        2048, 2048, 0, 4096, 2,
        0L, 512L * 2048, 0L, 0L, 4L * 512 * 4096, 512L * 4096, 2048L, 512L);
    // G3 qs[b][256][4096] = QW_all · cen_t[b]^T + q norm partials
    gemm_tn<128,128,4,4, 0,0, 0, 1><<<dim3(2, 32, 4), 256, 0, stream>>>(
        QWb, cenT, qs, cenT, zpg, nQp,
        256, 256, 256, 4096, 0,
        0L, 0L, 4096L * 256, 0L, 256L * 4096, 0L, 256L, 0L);
    // G5 raw score[bs][64][512] = qs · keys^T  (f32 out)
    gemm_tn<64,64,2,2, 0,0, 1, 0><<<dim3(1, 8, 16), 256, 0, stream>>>(
        qs, keys, score, cenT, zpg, nullptr,
        4096, 4096, 4096, 512, 2,
        256L * 4096, 64L * 4096, 4L * 512 * 4096, 512L * 4096, 4L * 64 * 512, 64L * 512, 0L, 0L);
    // norm-reduce + scale + instance-norm + softmax (+ wc)
    softmax_in<<<dim3(16), 256, 0, stream>>>(score, nQp, nKp, WSWC);

    // E: Xcomb[bs][64][0:2048] = ws · VW[s]   (ws rows in WSWC, stride 576)
    gemm_tn<64,128,2,4, 0,0, 0, 0><<<dim3(1, 16, 16), 256, 0, stream>>>(
        WSWC, VWt, Xcomb, cenT, zpg, nullptr,
        512, 576, 512, 2304, 2,
        4L * 64 * 576, 64L * 576, 0L, 2048L * 512, 4L * 64 * 2304, 64L * 2304, 0L, 0L);
    // F: Xcomb[bs][64][2048:2304] = wc · (-LW[s])  (wc at WSWC col 512)
    gemm_tn<64,128,2,4, 0,0, 0, 0><<<dim3(1, 2, 16), 256, 0, stream>>>(
        WSWC + 512, LWt, Xcomb + 2048, cenT, zpg, nullptr,
        64, 576, 64, 2304, 2,
        4L * 64 * 576, 64L * 576, 0L, 256L * 64, 4L * 64 * 2304, 64L * 2304, 0L, 0L);
    // G6n out1_t[b][4096][s*64+h] = [surr_t | cen_t] · Xcomb[bs]^T  (K=2304,
    // X gathered: k<2048 shifted, k>=2048 center)
    gemm_tn<128,64,4,2, 1,0, 0, 0><<<dim3(32, 1, 16), 256, 0, stream>>>(
        nullptr, Xcomb, out1t, cenT, zpg, nullptr,
        2304, 0, 2304, 256, 2,
        0L, 0L, 4L * 64 * 2304, 64L * 2304, 4096L * 256, 64L, 0L, 0L);

    // G7 out2b[b][256][4096] (bf16) = OW · out1_t[b]^T + BN stat partials
    gemm_tn<128,128,4,4, 0,0, 0, 2><<<dim3(2, 32, 4), 256, 0, stream>>>(
        OWb, out1t, out2b, cenT, zpg, bnp,
        256, 256, 256, 4096, 0,
        0L, 0L, 4096L * 256, 0L, 256L * 4096, 0L, 0L, 0L);

    bn_finalize<<<dim3(1), 256, 0, stream>>>(bnp, gamma, beta, bnst);
    bn_apply<<<dim3(2048), 256, 0, stream>>>(out2b, bnst, out);
}